// Round 8
// baseline (33.380 us; speedup 1.0000x reference)
//
#include <hip/hip_runtime.h>
#include <math.h>

#define LMAX   50
#define NB     4096
#define NJOB   (NB * 4)      // (element, tile) jobs, t = 0..3
#define NSLOTA 3072          // 768 blocks x 4 waves, all resident (3 blocks/CU)

typedef short bf16x8 __attribute__((ext_vector_type(8)));
typedef float f32x4  __attribute__((ext_vector_type(4)));
union bfu { bf16x8 v; unsigned u[4]; };

// ws layout (float offsets)
#define WS_PACC 0                    // [4096][4][64] tile partial weighted sums
#define WS_PM   (NB * 4 * 64)        // [4096][4] tile max
#define WS_PS   (WS_PM + NB * 4)     // [4096][4] tile expsum
#define WS_HN   (WS_PS + NB * 4)     // [4096][64] node-half preact

// packed f32 pair -> 2x bf16 (RNE)
__device__ __forceinline__ unsigned cvt_pk(float lo, float hi) {
    unsigned r;
    asm("v_cvt_pk_bf16_f32 %0, %1, %2" : "=v"(r) : "v"(lo), "v"(hi));
    return r;
}
__device__ __forceinline__ bf16x8 cvt8f(float4 a, float4 b) {
    bfu r;
    r.u[0] = cvt_pk(a.x, a.y); r.u[1] = cvt_pk(a.z, a.w);
    r.u[2] = cvt_pk(b.x, b.y); r.u[3] = cvt_pk(b.z, b.w);
    return r.v;
}
__device__ __forceinline__ float bf2f(short s) {
    union { unsigned u; float f; } v; v.u = ((unsigned)(unsigned short)s) << 16;
    return v.f;
}

// ---------- kernel 0: hn[e][n] = b1[n] + u[nodes[e]] @ W1[64:128] ----------
__global__ __launch_bounds__(256) void hn_k(
    const float* __restrict__ u_table, const float* __restrict__ W1,
    const float* __restrict__ b1, const int* __restrict__ nodes,
    float* __restrict__ hn_all)
{
    __shared__ __attribute__((aligned(16))) short WN[8][64][8];
    const int tid = threadIdx.x;
    const int w = tid >> 6, lane = tid & 63;
    const int l15 = lane & 15, g = lane >> 4, g8 = g * 8;

    for (int f = w; f < 8; f += 4) {               // node-half B-frags
        const int ks = f >> 2, nt = f & 3;
        const float* p = W1 + (64 + ks * 32 + g8) * 64 + nt * 16 + l15;
        bfu r;
        r.u[0] = cvt_pk(p[0],   p[64]);
        r.u[1] = cvt_pk(p[128], p[192]);
        r.u[2] = cvt_pk(p[256], p[320]);
        r.u[3] = cvt_pk(p[384], p[448]);
        *(bf16x8*)&WN[f][lane][0] = r.v;
    }
    __syncthreads();

    const int base = (blockIdx.x * 4 + w) * 16;    // 64 blocks x 4 waves x 16 elems
    const int nd = nodes[base + l15];              // A-row l15 = element base+l15
    const float* up = u_table + (size_t)nd * 64 + g8;
    float4 u0 = *(const float4*)(up);
    float4 u1 = *(const float4*)(up + 4);
    float4 u2 = *(const float4*)(up + 32);
    float4 u3 = *(const float4*)(up + 36);
    bf16x8 au0 = cvt8f(u0, u1), au1 = cvt8f(u2, u3);

    #pragma unroll
    for (int nt = 0; nt < 4; ++nt) {
        const float bv = b1[nt * 16 + l15];
        f32x4 c = { bv, bv, bv, bv };
        c = __builtin_amdgcn_mfma_f32_16x16x32_bf16(au0, *(const bf16x8*)&WN[nt][lane][0], c, 0, 0, 0);
        c = __builtin_amdgcn_mfma_f32_16x16x32_bf16(au1, *(const bf16x8*)&WN[4 + nt][lane][0], c, 0, 0, 0);
        #pragma unroll
        for (int reg = 0; reg < 4; ++reg)          // C row g*4+reg -> element
            hn_all[(size_t)(base + g * 4 + reg) * 64 + nt * 16 + l15] = c[reg];
    }
}

// ---------- kernel A: per-(element,tile) partial softmax aggregates ----------
__global__ __launch_bounds__(256, 3) void tile_k(
    const float* __restrict__ i_table,
    const float* __restrict__ W1, const float* __restrict__ W2,
    const float* __restrict__ b2, const float* __restrict__ W3,
    const int* __restrict__ neighbors, const int* __restrict__ lengths,
    const float* __restrict__ hn_all,
    float* __restrict__ pacc, float* __restrict__ pm, float* __restrict__ ps)
{
    __shared__ __attribute__((aligned(16))) short WF[16][64][8];            // 16 KB
    __shared__ __attribute__((aligned(16))) unsigned short Hs[4][16 * 72];  // 9.2 KB
    __shared__ float Ls[4][16];

    const int tid = threadIdx.x;
    const int w = tid >> 6, lane = tid & 63;
    const int l15 = lane & 15, g = lane >> 4, g8 = g * 8;

    // stage W1-neighbor (f 0..7) + W2 (f 8..15) as B-frags, once per block
    for (int f = w; f < 16; f += 4) {
        const float* Ws = (f < 8) ? W1 : W2;
        const int fi = f & 7;
        const int ks = fi >> 2, nt = fi & 3;
        const float* p = Ws + (ks * 32 + g8) * 64 + nt * 16 + l15;
        bfu r;
        r.u[0] = cvt_pk(p[0],   p[64]);
        r.u[1] = cvt_pk(p[128], p[192]);
        r.u[2] = cvt_pk(p[256], p[320]);
        r.u[3] = cvt_pk(p[384], p[448]);
        *(bf16x8*)&WF[f][lane][0] = r.v;
    }
    __syncthreads();

    bf16x8 w1f[2][4], w2f[2][4];   // 64 VGPR, persistent
    #pragma unroll
    for (int ks = 0; ks < 2; ++ks)
        #pragma unroll
        for (int nt = 0; nt < 4; ++nt) {
            w1f[ks][nt] = *(const bf16x8*)&WF[ks * 4 + nt][lane][0];
            w2f[ks][nt] = *(const bf16x8*)&WF[8 + ks * 4 + nt][lane][0];
        }
    float b2v[4], w3v[4];
    #pragma unroll
    for (int nt = 0; nt < 4; ++nt) {
        b2v[nt] = b2[nt * 16 + l15];
        w3v[nt] = W3[nt * 16 + l15];
    }
    // b3 is softmax-invariant; skip.

    unsigned short* hw  = &Hs[w][0];
    float*          Lsw = &Ls[w][0];

    const int wslot = blockIdx.x * 4 + w;
    for (int j = wslot; j < NJOB; j += NSLOTA) {
        const int e = j >> 2, t = j & 3;
        const int len = lengths[e];
        if (t * 16 >= len) continue;               // wave-uniform skip

        int r = t * 16 + l15; if (r >= len) r = len - 1;   // clamp; masked at logit
        const int nbr = neighbors[e * LMAX + r];
        const float* xp = i_table + (size_t)nbr * 64 + g8;
        float4 x0 = *(const float4*)(xp);
        float4 x1 = *(const float4*)(xp + 4);
        float4 x2 = *(const float4*)(xp + 32);
        float4 x3 = *(const float4*)(xp + 36);
        // node-half preact (independent; issues alongside gathers)
        float hv0 = hn_all[e * 64 +  0 + l15];
        float hv1 = hn_all[e * 64 + 16 + l15];
        float hv2 = hn_all[e * 64 + 32 + l15];
        float hv3 = hn_all[e * 64 + 48 + l15];

        bf16x8 a0 = cvt8f(x0, x1), a1 = cvt8f(x2, x3);

        // ---- layer 1 (neighbor half on top of hn) ----
        f32x4 acc[4];
        acc[0] = (f32x4){hv0, hv0, hv0, hv0};
        acc[1] = (f32x4){hv1, hv1, hv1, hv1};
        acc[2] = (f32x4){hv2, hv2, hv2, hv2};
        acc[3] = (f32x4){hv3, hv3, hv3, hv3};
        #pragma unroll
        for (int nt = 0; nt < 4; ++nt)
            acc[nt] = __builtin_amdgcn_mfma_f32_16x16x32_bf16(a0, w1f[0][nt], acc[nt], 0, 0, 0);
        #pragma unroll
        for (int nt = 0; nt < 4; ++nt)
            acc[nt] = __builtin_amdgcn_mfma_f32_16x16x32_bf16(a1, w1f[1][nt], acc[nt], 0, 0, 0);

        // relu -> bf16 -> per-wave LDS transpose (C: row g*4+reg, col nt*16+l15)
        #pragma unroll
        for (int nt = 0; nt < 4; ++nt) {
            unsigned p0 = cvt_pk(fmaxf(acc[nt][0], 0.f), fmaxf(acc[nt][1], 0.f));
            unsigned p1 = cvt_pk(fmaxf(acc[nt][2], 0.f), fmaxf(acc[nt][3], 0.f));
            hw[(g * 4 + 0) * 72 + nt * 16 + l15] = (unsigned short)p0;
            hw[(g * 4 + 1) * 72 + nt * 16 + l15] = (unsigned short)(p0 >> 16);
            hw[(g * 4 + 2) * 72 + nt * 16 + l15] = (unsigned short)p1;
            hw[(g * 4 + 3) * 72 + nt * 16 + l15] = (unsigned short)(p1 >> 16);
        }
        bf16x8 h0 = *(const bf16x8*)&hw[l15 * 72 + g8];
        bf16x8 h1 = *(const bf16x8*)&hw[l15 * 72 + 32 + g8];

        // ---- layer 2 ----
        f32x4 c2[4];
        #pragma unroll
        for (int nt = 0; nt < 4; ++nt)
            c2[nt] = (f32x4){b2v[nt], b2v[nt], b2v[nt], b2v[nt]};
        #pragma unroll
        for (int nt = 0; nt < 4; ++nt)
            c2[nt] = __builtin_amdgcn_mfma_f32_16x16x32_bf16(h0, w2f[0][nt], c2[nt], 0, 0, 0);
        #pragma unroll
        for (int nt = 0; nt < 4; ++nt)
            c2[nt] = __builtin_amdgcn_mfma_f32_16x16x32_bf16(h1, w2f[1][nt], c2[nt], 0, 0, 0);

        // ---- tile logits (row g*4+reg), reduce over n within group ----
        float sv[4];
        #pragma unroll
        for (int reg = 0; reg < 4; ++reg) {
            float s = 0.f;
            #pragma unroll
            for (int nt = 0; nt < 4; ++nt)
                s = fmaf(fmaxf(c2[nt][reg], 0.f), w3v[nt], s);
            s += __shfl_xor(s, 1); s += __shfl_xor(s, 2);
            s += __shfl_xor(s, 4); s += __shfl_xor(s, 8);
            if (t * 16 + g * 4 + reg >= len) s = -INFINITY;
            sv[reg] = s;
        }

        // ---- per-tile partial softmax ----
        float tm = fmaxf(fmaxf(sv[0], sv[1]), fmaxf(sv[2], sv[3]));
        tm = fmaxf(tm, __shfl_xor(tm, 16));
        tm = fmaxf(tm, __shfl_xor(tm, 32));        // tile max (valid rows only)
        const float e0 = __expf(sv[0] - tm), e1 = __expf(sv[1] - tm);
        const float e2 = __expf(sv[2] - tm), e3 = __expf(sv[3] - tm);
        float es = (e0 + e1) + (e2 + e3);
        es += __shfl_xor(es, 16);
        es += __shfl_xor(es, 32);                  // tile expsum, all lanes

        if (l15 == 0) *(float4*)&Lsw[g * 4] = make_float4(e0, e1, e2, e3);
        const float er = Lsw[l15];                 // e for row l15 (0 if masked)

        // partial weighted sum over this tile's rows: reduce over l15
        float aw[16];
        #pragma unroll
        for (int i = 0; i < 8; ++i) {
            aw[i]     = er * bf2f(a0[i]);
            aw[8 + i] = er * bf2f(a1[i]);
        }
        #pragma unroll
        for (int i = 0; i < 16; ++i) {
            aw[i] += __shfl_xor(aw[i], 1);
            aw[i] += __shfl_xor(aw[i], 2);
            aw[i] += __shfl_xor(aw[i], 4);
            aw[i] += __shfl_xor(aw[i], 8);
        }
        if (l15 == 0) {
            float* pb = pacc + ((size_t)e * 4 + t) * 64;
            *(float4*)(pb + g8)          = make_float4(aw[0],  aw[1],  aw[2],  aw[3]);
            *(float4*)(pb + g8 + 4)      = make_float4(aw[4],  aw[5],  aw[6],  aw[7]);
            *(float4*)(pb + 32 + g8)     = make_float4(aw[8],  aw[9],  aw[10], aw[11]);
            *(float4*)(pb + 32 + g8 + 4) = make_float4(aw[12], aw[13], aw[14], aw[15]);
        }
        if (lane == 0) { pm[e * 4 + t] = tm; ps[e * 4 + t] = es; }
    }
}

// ---------- kernel B: flash-combine of <=4 tile partials per element ----------
__global__ __launch_bounds__(512) void combine_k(
    const int* __restrict__ lengths,
    const float* __restrict__ pacc, const float* __restrict__ pm,
    const float* __restrict__ ps, float* __restrict__ out)
{
    const int tid = threadIdx.x;
    const int w = tid >> 6, lane = tid & 63;
    const int e = blockIdx.x * 8 + w;
    const int len = lengths[e];
    const int ntl = (len + 15) >> 4;

    float pmv = (lane < ntl) ? pm[e * 4 + lane] : -INFINITY;
    float mx = pmv;
    #pragma unroll
    for (int off = 1; off < 64; off <<= 1) mx = fmaxf(mx, __shfl_xor(mx, off));
    const float sc  = (lane < ntl) ? __expf(pmv - mx) : 0.f;
    const float pss = (lane < ntl) ? ps[e * 4 + lane] * sc : 0.f;
    float denom = pss;
    #pragma unroll
    for (int off = 1; off < 64; off <<= 1) denom += __shfl_xor(denom, off);

    float num = 0.f;                 // lane = output dim
    const float* pb = pacc + (size_t)e * 256;
    #pragma unroll
    for (int t = 0; t < 4; ++t) {
        const float sct = __shfl(sc, t);   // 0 for t >= ntl
        if (t < ntl) num = fmaf(sct, pb[t * 64 + lane], num);
    }
    out[e * 64 + lane] = num / denom;
}

extern "C" void kernel_launch(void* const* d_in, const int* in_sizes, int n_in,
                              void* d_out, int out_size, void* d_ws, size_t ws_size,
                              hipStream_t stream) {
    const float* u_table   = (const float*)d_in[0];
    const float* i_table   = (const float*)d_in[1];
    const float* W1        = (const float*)d_in[2];
    const float* b1        = (const float*)d_in[3];
    const float* W2        = (const float*)d_in[4];
    const float* b2        = (const float*)d_in[5];
    const float* W3        = (const float*)d_in[6];
    // d_in[7] = b3: softmax-invariant, unused
    const int*   nodes     = (const int*)d_in[8];
    const int*   neighbors = (const int*)d_in[9];
    const int*   lengths   = (const int*)d_in[10];
    float* out = (float*)d_out;
    float* ws  = (float*)d_ws;

    hn_k<<<dim3(64), dim3(256), 0, stream>>>(u_table, W1, b1, nodes, ws + WS_HN);
    tile_k<<<dim3(NSLOTA / 4), dim3(256), 0, stream>>>(
        i_table, W1, W2, b2, W3, neighbors, lengths,
        ws + WS_HN, ws + WS_PACC, ws + WS_PM, ws + WS_PS);
    combine_k<<<dim3(NB / 8), dim3(512), 0, stream>>>(
        lengths, ws + WS_PACC, ws + WS_PM, ws + WS_PS, out);
}

// Round 9
// 25.109 us; speedup vs baseline: 1.3294x; 1.3294x over previous
//
#include <hip/hip_runtime.h>
#include <math.h>

#define LMAX 50
#define NB   4096

typedef short bf16x8 __attribute__((ext_vector_type(8)));
typedef float f32x4  __attribute__((ext_vector_type(4)));
union bfu { bf16x8 v; unsigned u[4]; };

// packed f32 pair -> 2x bf16 (RNE), single VALU instr
__device__ __forceinline__ unsigned cvt_pk(float lo, float hi) {
    unsigned r;
    asm("v_cvt_pk_bf16_f32 %0, %1, %2" : "=v"(r) : "v"(lo), "v"(hi));
    return r;
}
__device__ __forceinline__ bf16x8 cvt8f(float4 a, float4 b) {
    bfu r;
    r.u[0] = cvt_pk(a.x, a.y); r.u[1] = cvt_pk(a.z, a.w);
    r.u[2] = cvt_pk(b.x, b.y); r.u[3] = cvt_pk(b.z, b.w);
    return r.v;
}
__device__ __forceinline__ float bf2f(short s) {
    union { unsigned u; float f; } v; v.u = ((unsigned)(unsigned short)s) << 16;
    return v.f;
}

// one wave = one batch element; all neighbor gathers issued up-front with the
// len-dependency cut out of the idx chain (static clamp + readlane fallback).
__global__ __launch_bounds__(256, 2) void graphrec_k(
    const float* __restrict__ u_table, const float* __restrict__ i_table,
    const float* __restrict__ W1, const float* __restrict__ b1,
    const float* __restrict__ W2, const float* __restrict__ b2,
    const float* __restrict__ W3, const float* __restrict__ b3,
    const int* __restrict__ nodes, const int* __restrict__ neighbors,
    const int* __restrict__ lengths, float* __restrict__ out)
{
    __shared__ __attribute__((aligned(16))) short WL[24][64][8];            // 24.5 KB
    __shared__ __attribute__((aligned(16))) unsigned short Hs[4][16 * 72];  //  9.2 KB
    __shared__ float Ls[4][16];

    const int tid = threadIdx.x;
    const int w = tid >> 6, lane = tid & 63;
    const int l15 = lane & 15, g = lane >> 4, g8 = g * 8;

    // ---- element loads first: longest chains go airborne immediately ----
    const int b   = blockIdx.x * 4 + w;     // one element per wave
    const int len = lengths[b];
    const int nd  = nodes[b];

    // len-FREE idx loads (static clamp only at t=3)
    int idxs[4];
    idxs[0] = neighbors[b * LMAX + l15];
    idxs[1] = neighbors[b * LMAX + 16 + l15];
    idxs[2] = neighbors[b * LMAX + 32 + l15];
    idxs[3] = neighbors[b * LMAX + min(48 + l15, LMAX - 1)];

    // biases / W3 (row layout, tiny)
    float b1v[4], b2v[4], w3v[4];
    #pragma unroll
    for (int nt = 0; nt < 4; ++nt) {
        b1v[nt] = b1[nt * 16 + l15];
        b2v[nt] = b2[nt * 16 + l15];
        w3v[nt] = W3[nt * 16 + l15];
    }
    // b3 shifts all logits equally -> softmax-invariant, skip.

    // u-row gather (chain: nodes -> u)
    const float* up = u_table + (size_t)nd * 64 + g8;
    const float4 un0 = *(const float4*)(up);
    const float4 un1 = *(const float4*)(up + 4);
    const float4 un2 = *(const float4*)(up + 32);
    const float4 un3 = *(const float4*)(up + 36);

    // ---- ALL x-row gathers issued up-front (invalid lanes -> row t*16) ----
    const int ntl = (len + 15) >> 4;
    float4 LA[4][4];
    #pragma unroll
    for (int t = 0; t < 4; ++t) {
        if (t < ntl) {
            const int fbv = __builtin_amdgcn_readlane(idxs[t], 0);  // row t*16 (valid)
            const int rr  = t * 16 + l15;
            const int a   = (rr < len) ? idxs[t] : fbv;
            const float* xp = i_table + (size_t)a * 64 + g8;
            LA[t][0] = *(const float4*)(xp);
            LA[t][1] = *(const float4*)(xp + 4);
            LA[t][2] = *(const float4*)(xp + 32);
            LA[t][3] = *(const float4*)(xp + 36);
        }
    }

    // ---- cooperative weight staging as B-frags: lane(l15,g) holds B[k][n],
    //      n = nt*16+l15, k = ks*32 + g*8 + i.  f 0..7: W1 neighbor half,
    //      f 8..15: W1 node half, f 16..23: W2. ----
    for (int f = w; f < 24; f += 4) {
        const float* Ws = (f < 16) ? W1 : W2;
        const int fi = (f < 16) ? f : f - 16;
        const int ks = fi >> 2, nt = fi & 3;
        const float* p = Ws + (ks * 32 + g8) * 64 + nt * 16 + l15;
        bfu r;
        r.u[0] = cvt_pk(p[0],   p[64]);
        r.u[1] = cvt_pk(p[128], p[192]);
        r.u[2] = cvt_pk(p[256], p[320]);
        r.u[3] = cvt_pk(p[384], p[448]);
        *(bf16x8*)&WL[f][lane][0] = r.v;
    }
    __syncthreads();   // drains all loads -- everything needed is already in flight

    // neighbor-half W1 + W2 frags persistent in VGPRs (64)
    bf16x8 w1f[2][4], w2f[2][4];
    #pragma unroll
    for (int ks = 0; ks < 2; ++ks)
        #pragma unroll
        for (int nt = 0; nt < 4; ++nt) {
            w1f[ks][nt] = *(const bf16x8*)&WL[ks * 4 + nt][lane][0];
            w2f[ks][nt] = *(const bf16x8*)&WL[16 + ks * 4 + nt][lane][0];
        }

    // ---- node half of layer 1 (node frags read once from LDS) ----
    bf16x8 axu0 = cvt8f(un0, un1), axu1 = cvt8f(un2, un3);
    f32x4 hn[4];
    #pragma unroll
    for (int nt = 0; nt < 4; ++nt) {
        f32x4 c = { b1v[nt], b1v[nt], b1v[nt], b1v[nt] };
        c = __builtin_amdgcn_mfma_f32_16x16x32_bf16(axu0, *(const bf16x8*)&WL[8  + nt][lane][0], c, 0, 0, 0);
        c = __builtin_amdgcn_mfma_f32_16x16x32_bf16(axu1, *(const bf16x8*)&WL[12 + nt][lane][0], c, 0, 0, 0);
        hn[nt] = c;
    }

    float m = -INFINITY, ssum = 0.f;
    float accW[16];
    #pragma unroll
    for (int i = 0; i < 16; ++i) accW[i] = 0.f;

    unsigned short* hw  = &Hs[w][0];
    float*          Lsw = &Ls[w][0];

    #pragma unroll
    for (int t = 0; t < 4; ++t) {
        if (t < ntl) {
            bf16x8 a0 = cvt8f(LA[t][0], LA[t][1]);
            bf16x8 a1 = cvt8f(LA[t][2], LA[t][3]);

            // ---- layer 1 (neighbor half) on top of hn ----
            f32x4 acc[4];
            #pragma unroll
            for (int nt = 0; nt < 4; ++nt) acc[nt] = hn[nt];
            #pragma unroll
            for (int nt = 0; nt < 4; ++nt)
                acc[nt] = __builtin_amdgcn_mfma_f32_16x16x32_bf16(a0, w1f[0][nt], acc[nt], 0, 0, 0);
            #pragma unroll
            for (int nt = 0; nt < 4; ++nt)
                acc[nt] = __builtin_amdgcn_mfma_f32_16x16x32_bf16(a1, w1f[1][nt], acc[nt], 0, 0, 0);

            // relu -> bf16 -> per-wave LDS transpose (C: row g*4+reg, col nt*16+l15)
            #pragma unroll
            for (int nt = 0; nt < 4; ++nt) {
                unsigned p0 = cvt_pk(fmaxf(acc[nt][0], 0.f), fmaxf(acc[nt][1], 0.f));
                unsigned p1 = cvt_pk(fmaxf(acc[nt][2], 0.f), fmaxf(acc[nt][3], 0.f));
                hw[(g * 4 + 0) * 72 + nt * 16 + l15] = (unsigned short)p0;
                hw[(g * 4 + 1) * 72 + nt * 16 + l15] = (unsigned short)(p0 >> 16);
                hw[(g * 4 + 2) * 72 + nt * 16 + l15] = (unsigned short)p1;
                hw[(g * 4 + 3) * 72 + nt * 16 + l15] = (unsigned short)(p1 >> 16);
            }
            bf16x8 h0 = *(const bf16x8*)&hw[l15 * 72 + g8];
            bf16x8 h1 = *(const bf16x8*)&hw[l15 * 72 + 32 + g8];

            // ---- layer 2 ----
            f32x4 c2[4];
            #pragma unroll
            for (int nt = 0; nt < 4; ++nt)
                c2[nt] = (f32x4){b2v[nt], b2v[nt], b2v[nt], b2v[nt]};
            #pragma unroll
            for (int nt = 0; nt < 4; ++nt)
                c2[nt] = __builtin_amdgcn_mfma_f32_16x16x32_bf16(h0, w2f[0][nt], c2[nt], 0, 0, 0);
            #pragma unroll
            for (int nt = 0; nt < 4; ++nt)
                c2[nt] = __builtin_amdgcn_mfma_f32_16x16x32_bf16(h1, w2f[1][nt], c2[nt], 0, 0, 0);

            // ---- layer 3 logits (row g*4+reg), reduce over n within group ----
            float sv[4];
            #pragma unroll
            for (int reg = 0; reg < 4; ++reg) {
                float s = 0.f;
                #pragma unroll
                for (int nt = 0; nt < 4; ++nt)
                    s = fmaf(fmaxf(c2[nt][reg], 0.f), w3v[nt], s);
                s += __shfl_xor(s, 1); s += __shfl_xor(s, 2);
                s += __shfl_xor(s, 4); s += __shfl_xor(s, 8);
                if (t * 16 + g * 4 + reg >= len) s = -INFINITY;
                sv[reg] = s;
            }

            // ---- online softmax (wave-uniform running state) ----
            float tm = fmaxf(fmaxf(sv[0], sv[1]), fmaxf(sv[2], sv[3]));
            tm = fmaxf(tm, __shfl_xor(tm, 16));
            tm = fmaxf(tm, __shfl_xor(tm, 32));
            if (tm > m) {
                const float sc = __expf(m - tm);   // first tile: exp(-inf)=0
                ssum *= sc;
                #pragma unroll
                for (int i = 0; i < 16; ++i) accW[i] *= sc;
                m = tm;
            }
            float e0 = __expf(sv[0] - m), e1 = __expf(sv[1] - m);
            float e2 = __expf(sv[2] - m), e3 = __expf(sv[3] - m);
            float es = (e0 + e1) + (e2 + e3);
            es += __shfl_xor(es, 16);
            es += __shfl_xor(es, 32);
            ssum += es;

            // broadcast e to row owners via per-wave LDS
            if (l15 == 0) *(float4*)&Lsw[g * 4] = make_float4(e0, e1, e2, e3);
            const float er = Lsw[l15];             // e for tile row l15 (0 if masked)

            // weighted-x partials straight from the A-fragments
            #pragma unroll
            for (int i = 0; i < 8; ++i) {
                accW[i]     = fmaf(er, bf2f(a0[i]), accW[i]);
                accW[8 + i] = fmaf(er, bf2f(a1[i]), accW[8 + i]);
            }
        }
    }

    // ---- finalize: reduce over the 16 tile rows (l15), write 64 dims ----
    #pragma unroll
    for (int i = 0; i < 16; ++i) {
        accW[i] += __shfl_xor(accW[i], 1);
        accW[i] += __shfl_xor(accW[i], 2);
        accW[i] += __shfl_xor(accW[i], 4);
        accW[i] += __shfl_xor(accW[i], 8);
    }
    const float inv = 1.f / ssum;
    if (l15 == 0) {
        float4 o0 = make_float4(accW[0]  * inv, accW[1]  * inv, accW[2]  * inv, accW[3]  * inv);
        float4 o1 = make_float4(accW[4]  * inv, accW[5]  * inv, accW[6]  * inv, accW[7]  * inv);
        float4 o2 = make_float4(accW[8]  * inv, accW[9]  * inv, accW[10] * inv, accW[11] * inv);
        float4 o3 = make_float4(accW[12] * inv, accW[13] * inv, accW[14] * inv, accW[15] * inv);
        *(float4*)(out + b * 64 +      g8)     = o0;
        *(float4*)(out + b * 64 +      g8 + 4) = o1;
        *(float4*)(out + b * 64 + 32 + g8)     = o2;
        *(float4*)(out + b * 64 + 32 + g8 + 4) = o3;
    }
}

extern "C" void kernel_launch(void* const* d_in, const int* in_sizes, int n_in,
                              void* d_out, int out_size, void* d_ws, size_t ws_size,
                              hipStream_t stream) {
    const float* u_table   = (const float*)d_in[0];
    const float* i_table   = (const float*)d_in[1];
    const float* W1        = (const float*)d_in[2];
    const float* b1        = (const float*)d_in[3];
    const float* W2        = (const float*)d_in[4];
    const float* b2        = (const float*)d_in[5];
    const float* W3        = (const float*)d_in[6];
    const float* b3        = (const float*)d_in[7];
    const int*   nodes     = (const int*)d_in[8];
    const int*   neighbors = (const int*)d_in[9];
    const int*   lengths   = (const int*)d_in[10];
    float* out = (float*)d_out;

    graphrec_k<<<dim3(NB / 4), dim3(256), 0, stream>>>(
        u_table, i_table, W1, b1, W2, b2, W3, b3, nodes, neighbors, lengths, out);
}